// Round 9
// baseline (225.107 us; speedup 1.0000x reference)
//
#include <hip/hip_runtime.h>
#include <hip/hip_bf16.h>

// B=4, T=2048, D=1024, L=512, H=8, Lh=64, Dh=128. Chunks: NC=16 of G=128.
// 6-launch pipeline:
//  1 prep_inputs: X->bf16, W->W^T bf16 (WqkT = [WqT;WkT])
//  2 qkv_gemm:  x<8: [Qs|K]=X@[Wq|Wk] (softmax / chunk-stats epilogues)
//               x>=8: VT[bh][d][t]=(X@Wv)^T via LDS-transpose epilogue
//               LDS is a union: As/Bs (K-loop) | Ts (V epi) | sred (stats epi)
//  3 prep_scan_sums: M,A0 combine; a=exp(K-M), A prefix, P=Qs/A; aT in LDS;
//                    S_c^T[d,l] = V^T @ a via MFMA -> bf16
//  4 chunk_prefix: exclusive prefix of S over chunks (fp32 accum, bf16 store)
//  5 chunk_out_mfma: G^T=A@P^T, mask, Y = Gm@V + P@C0
//  6 mfma_gemm: out = Y@Wo (fp32)

typedef __attribute__((ext_vector_type(8))) short bf16x8;
typedef __attribute__((ext_vector_type(4))) float f32x4;

__device__ inline ushort f2bf(float f) {
    unsigned u = __float_as_uint(f);
    unsigned r = (u + 0x7fff + ((u >> 16) & 1)) >> 16;
    return (ushort)r;
}
__device__ inline float bf2f(ushort h) { return __uint_as_float(((unsigned)h) << 16); }

__device__ inline void gload_lds16(const ushort* g, ushort* l) {
    __builtin_amdgcn_global_load_lds((const __attribute__((address_space(1))) void*)g,
                                     (__attribute__((address_space(3))) void*)l, 16, 0, 0);
}

// blocks [0,8192): X fp32 -> bf16. blocks [8192,11264): weight transpose tiles.
__global__ __launch_bounds__(256) void prep_inputs_kernel(const float* __restrict__ X,
                                                          const float* __restrict__ Wq,
                                                          const float* __restrict__ Wk,
                                                          const float* __restrict__ Wv,
                                                          const float* __restrict__ Wo,
                                                          ushort* __restrict__ Xb,
                                                          ushort* __restrict__ WqkT,
                                                          ushort* __restrict__ WvT,
                                                          ushort* __restrict__ WoT) {
    if (blockIdx.x < 8192) {
        int i = blockIdx.x * 1024 + threadIdx.x * 4;
        float4 v = *(const float4*)(X + i);
        ushort4 o = {f2bf(v.x), f2bf(v.y), f2bf(v.z), f2bf(v.w)};
        *(ushort4*)(Xb + i) = o;
        return;
    }
    __shared__ float s[32][33];
    int t = blockIdx.x - 8192;
    const float* W; ushort* WT; int N, tile, rowoff;
    if (t < 512)       { W = Wq; WT = WqkT; N = 512;  tile = t;        rowoff = 0; }
    else if (t < 1024) { W = Wk; WT = WqkT; N = 512;  tile = t - 512;  rowoff = 512; }
    else if (t < 2048) { W = Wv; WT = WvT;  N = 1024; tile = t - 1024; rowoff = 0; }
    else               { W = Wo; WT = WoT;  N = 1024; tile = t - 2048; rowoff = 0; }
    int tilesX = N >> 5;
    int n0 = (tile % tilesX) * 32, k0 = (tile / tilesX) * 32;
    int tx = threadIdx.x & 31, ty0 = threadIdx.x >> 5;
#pragma unroll
    for (int r = 0; r < 4; ++r) {
        int row = ty0 + r * 8;
        s[row][tx] = W[(size_t)(k0 + row) * N + n0 + tx];
    }
    __syncthreads();
#pragma unroll
    for (int r = 0; r < 4; ++r) {
        int row = ty0 + r * 8;
        WT[(size_t)(rowoff + n0 + row) * 1024 + k0 + tx] = f2bf(s[tx][row]);
    }
}

// Merged QKV GEMM: grid (16,64). x<8: C=[Qs|K] (N=1024), softmax (Q cols) or
// chunk-stats+bf16 K (K cols). x>=8: V with LDS-transposed VT epilogue.
// Single LDS union (34816 B): [As|Bs] during K-loop; Ts or sredM/sredS after.
__global__ __launch_bounds__(256) void qkv_gemm(const ushort* __restrict__ A,
                                                const ushort* __restrict__ WqkT,
                                                const ushort* __restrict__ WvT,
                                                ushort* __restrict__ Qb,
                                                ushort* __restrict__ Kbp,
                                                ushort* __restrict__ VT,
                                                float* __restrict__ mbuf,
                                                float* __restrict__ sbuf) {
    __shared__ __align__(16) ushort smem[128 * 136];  // 34816 B union
    ushort* As = smem;                 // 4096 ushorts
    ushort* Bs = smem + 4096;          // 4096 ushorts
    ushort* Ts = smem;                 // 128*136 ushorts (V epilogue)
    float* sredM = (float*)smem;       // 2*128 floats (stats epilogue)
    float* sredS = sredM + 256;
    const int K = 1024;
    const int tid = threadIdx.x;
    const int w = tid >> 6, lane = tid & 63;
    const int quad = lane >> 4, l15 = lane & 15;
    const bool isQK = blockIdx.x < 8;
    const int nx = isQK ? blockIdx.x : (blockIdx.x - 8);
    const ushort* BT = isQK ? WqkT : WvT;
    const int m0 = blockIdx.y * 128, n0 = nx * 128;
    const int wm = (w & 1) * 64, wn = (w >> 1) * 64;
    f32x4 acc[4][4] = {};
    const int r0 = tid >> 2, kc = (tid & 3) * 8;
    const int r1 = 64 + r0;
    const ushort* Arow0 = A + (size_t)(m0 + r0) * K + kc;
    const ushort* Arow1 = A + (size_t)(m0 + r1) * K + kc;
    const ushort* Brow0 = BT + (size_t)(n0 + r0) * K + kc;
    const ushort* Brow1 = BT + (size_t)(n0 + r1) * K + kc;
    ushort* AsW0 = As + (w * 64) * 8;
    ushort* AsW1 = As + (256 + w * 64) * 8;
    ushort* BsW0 = Bs + (w * 64) * 8;
    ushort* BsW1 = Bs + (256 + w * 64) * 8;
    const ushort* afp = As + (wm + l15) * 32 + quad * 8;
    const ushort* bfp = Bs + (wn + l15) * 32 + quad * 8;
    for (int k0 = 0; k0 < K; k0 += 32) {
        gload_lds16(Arow0 + k0, AsW0);
        gload_lds16(Arow1 + k0, AsW1);
        gload_lds16(Brow0 + k0, BsW0);
        gload_lds16(Brow1 + k0, BsW1);
        __syncthreads();
        bf16x8 af[4], bf[4];
#pragma unroll
        for (int i = 0; i < 4; ++i) {
            af[i] = *(const bf16x8*)(afp + i * 16 * 32);
            bf[i] = *(const bf16x8*)(bfp + i * 16 * 32);
        }
#pragma unroll
        for (int i = 0; i < 4; ++i)
#pragma unroll
            for (int j = 0; j < 4; ++j)
                acc[i][j] = __builtin_amdgcn_mfma_f32_16x16x32_bf16(af[i], bf[j], acc[i][j], 0, 0, 0);
        __syncthreads();
    }
    // After the loop's trailing barrier, As/Bs are dead -> union reuse is safe.
    const int crow = m0 + wm + quad * 4;
    const int ccol = n0 + wn + l15;
    if (!isQK) {
        // VT epilogue: transpose tile through LDS, write 256B-contiguous runs.
#pragma unroll
        for (int i = 0; i < 4; ++i)
#pragma unroll
            for (int j = 0; j < 4; ++j) {
                f32x4 v = acc[i][j];
                int d = wn + j * 16 + l15;
                int t = wm + i * 16 + quad * 4;
                ushort4 o = {f2bf(v[0]), f2bf(v[1]), f2bf(v[2]), f2bf(v[3])};
                *(ushort4*)(Ts + d * 136 + t) = o;
            }
        __syncthreads();
        int b = m0 >> 11, tloc = m0 & 2047, h = n0 >> 7;
        ushort* base = VT + ((size_t)(b * 8 + h) * 128) * 2048 + tloc;
        int kk = tid & 7;
#pragma unroll
        for (int p = 0; p < 4; ++p) {
            int dd = p * 32 + (tid >> 3);
            const uint4* src = (const uint4*)(Ts + dd * 136 + kk * 16);
            uint4* dst = (uint4*)(base + (size_t)dd * 2048 + kk * 16);
            dst[0] = src[0];
            dst[1] = src[1];
        }
        return;
    }
    if (n0 < 512) {
        // softmax per row over this wave's 64-col stripe (= one head)
#pragma unroll
        for (int i = 0; i < 4; ++i)
#pragma unroll
            for (int r = 0; r < 4; ++r) {
                float x0 = acc[i][0][r], x1 = acc[i][1][r];
                float x2 = acc[i][2][r], x3 = acc[i][3][r];
                float m = fmaxf(fmaxf(x0, x1), fmaxf(x2, x3));
#pragma unroll
                for (int off = 1; off < 16; off <<= 1) m = fmaxf(m, __shfl_xor(m, off));
                float e0 = __expf(x0 - m), e1 = __expf(x1 - m);
                float e2 = __expf(x2 - m), e3 = __expf(x3 - m);
                float s = (e0 + e1) + (e2 + e3);
#pragma unroll
                for (int off = 1; off < 16; off <<= 1) s += __shfl_xor(s, off);
                float rs = 1.0f / s;
                acc[i][0][r] = e0 * rs; acc[i][1][r] = e1 * rs;
                acc[i][2][r] = e2 * rs; acc[i][3][r] = e3 * rs;
            }
#pragma unroll
        for (int i = 0; i < 4; ++i)
#pragma unroll
            for (int j = 0; j < 4; ++j) {
                f32x4 v = acc[i][j];
#pragma unroll
                for (int r = 0; r < 4; ++r)
                    Qb[(size_t)(crow + i * 16 + r) * 512 + ccol + j * 16] = f2bf(v[r]);
            }
    } else {
        // chunk stats over this block's 128 rows (= chunk c of batch b)
        int b = blockIdx.y >> 4, c = blockIdx.y & 15;
        float mj[4];
#pragma unroll
        for (int j = 0; j < 4; ++j) {
            float m = -1e30f;
#pragma unroll
            for (int i = 0; i < 4; ++i)
#pragma unroll
                for (int r = 0; r < 4; ++r) m = fmaxf(m, acc[i][j][r]);
            m = fmaxf(m, __shfl_xor(m, 16));
            m = fmaxf(m, __shfl_xor(m, 32));
            mj[j] = m;
        }
        if (quad == 0)
#pragma unroll
            for (int j = 0; j < 4; ++j) sredM[(w & 1) * 128 + (w >> 1) * 64 + j * 16 + l15] = mj[j];
        __syncthreads();
#pragma unroll
        for (int j = 0; j < 4; ++j) {
            int ci = (w >> 1) * 64 + j * 16 + l15;
            float M = fmaxf(sredM[ci], sredM[128 + ci]);
            float s = 0.f;
#pragma unroll
            for (int i = 0; i < 4; ++i)
#pragma unroll
                for (int r = 0; r < 4; ++r) s += __expf(acc[i][j][r] - M);
            s += __shfl_xor(s, 16);
            s += __shfl_xor(s, 32);
            mj[j] = s;
        }
        if (quad == 0)
#pragma unroll
            for (int j = 0; j < 4; ++j) sredS[(w & 1) * 128 + (w >> 1) * 64 + j * 16 + l15] = mj[j];
        __syncthreads();
        if (tid < 128) {
            int Kcol = (n0 - 512) + tid;
            int h = Kcol >> 6, l = Kcol & 63;
            int idx = (((b * 8 + h) * 16 + c)) * 64 + l;
            mbuf[idx] = fmaxf(sredM[tid], sredM[128 + tid]);
            sbuf[idx] = sredS[tid] + sredS[128 + tid];
        }
#pragma unroll
        for (int i = 0; i < 4; ++i)
#pragma unroll
            for (int j = 0; j < 4; ++j) {
                f32x4 v = acc[i][j];
#pragma unroll
                for (int r = 0; r < 4; ++r)
                    Kbp[(size_t)(crow + i * 16 + r) * 512 + (ccol - 512) + j * 16] = f2bf(v[r]);
            }
    }
}

// Block per (bh,c): combine stats -> M,A0; a = exp(K-M); A prefix; P = Qs/A;
// aT kept in LDS; then S_c^T[d,l] = V^T @ a via MFMA, written bf16.
__global__ __launch_bounds__(256) void prep_scan_sums_kernel(const ushort* __restrict__ Kbuf,
                                                             const ushort* __restrict__ Qs,
                                                             const float* __restrict__ mbuf,
                                                             const float* __restrict__ sbuf,
                                                             const ushort* __restrict__ VT,
                                                             ushort* __restrict__ abuf,
                                                             ushort* __restrict__ Pbuf,
                                                             ushort* __restrict__ Sb) {
    __shared__ float red[4][64];
    __shared__ __align__(16) ushort aS[64 * 136];  // [l][t], 272B rows (16B-aligned)
    int blk = blockIdx.x, bh = blk >> 4, c = blk & 15;
    int b = bh >> 3, h = bh & 7;
    int tg = threadIdx.x >> 6, l = threadIdx.x & 63;
    float mc[16];
#pragma unroll
    for (int cc = 0; cc < 16; ++cc) mc[cc] = mbuf[(bh * 16 + cc) * 64 + l];
    float M = -1e30f;
#pragma unroll
    for (int cc = 0; cc < 16; ++cc) M = fmaxf(M, mc[cc]);
    float A0 = 0.f;
    for (int cc = 0; cc < c; ++cc) A0 += sbuf[(bh * 16 + cc) * 64 + l] * __expf(mc[cc] - M);
    const ushort* kp = Kbuf + ((size_t)(b * 2048 + c * 128 + tg * 32)) * 512 + h * 64 + l;
    const ushort* qp = Qs + ((size_t)(b * 2048 + c * 128 + tg * 32)) * 512 + h * 64 + l;
    float a[32];
#pragma unroll
    for (int i = 0; i < 32; ++i) a[i] = __expf(bf2f(kp[(size_t)i * 512]) - M);
    float part = 0.f;
#pragma unroll
    for (int i = 0; i < 32; ++i) part += a[i];
    red[tg][l] = part;
    __syncthreads();
    float A = A0;
    for (int g = 0; g < 4; ++g) {
        float v = red[g][l];
        A += (g < tg) ? v : 0.f;
    }
    ushort* ap = abuf + ((size_t)(bh * 2048 + c * 128 + tg * 32)) * 64 + l;
    ushort* pp = Pbuf + ((size_t)(bh * 2048 + c * 128 + tg * 32)) * 64 + l;
    ushort atmp[32];
#pragma unroll
    for (int i = 0; i < 32; ++i) {
        A += a[i];
        ushort ab16 = f2bf(a[i]);
        ap[(size_t)i * 64] = ab16;
        atmp[i] = ab16;
        pp[(size_t)i * 64] = f2bf(bf2f(qp[(size_t)i * 512]) / A);
    }
    ushort* asp = aS + l * 136 + tg * 32;
#pragma unroll
    for (int v = 0; v < 4; ++v) *(uint4*)(asp + v * 8) = *(const uint4*)(atmp + v * 8);
    __syncthreads();
    // S^T[d,l] = sum_t V^T[d,t] a[t,l]; A-frag from VT (global), B-frag from aS.
    int w = threadIdx.x >> 6, lane = threadIdx.x & 63;
    int quad = lane >> 4, l15 = lane & 15;
    const ushort* vtb = VT + (size_t)bh * 128 * 2048 + c * 128;
    f32x4 acc[2][4] = {};
#pragma unroll
    for (int ks = 0; ks < 4; ++ks) {
        bf16x8 af[2];
#pragma unroll
        for (int mi = 0; mi < 2; ++mi)
            af[mi] = *(const bf16x8*)(vtb + (size_t)(w * 32 + mi * 16 + l15) * 2048 + ks * 32 + quad * 8);
#pragma unroll
        for (int nj = 0; nj < 4; ++nj) {
            bf16x8 bfr = *(const bf16x8*)(aS + (nj * 16 + l15) * 136 + ks * 32 + quad * 8);
#pragma unroll
            for (int mi = 0; mi < 2; ++mi)
                acc[mi][nj] = __builtin_amdgcn_mfma_f32_16x16x32_bf16(af[mi], bfr, acc[mi][nj], 0, 0, 0);
        }
    }
    ushort* sp = Sb + (size_t)blk * 8192;
#pragma unroll
    for (int mi = 0; mi < 2; ++mi)
#pragma unroll
        for (int nj = 0; nj < 4; ++nj) {
            f32x4 v = acc[mi][nj];
#pragma unroll
            for (int r = 0; r < 4; ++r)
                sp[(w * 32 + mi * 16 + quad * 4 + r) * 64 + nj * 16 + l15] = f2bf(v[r]);
        }
}

// In-place exclusive prefix over the 16 chunks; S bf16 [bh][c][d][l], fp32 accum.
__global__ __launch_bounds__(256) void chunk_prefix_kernel(ushort* __restrict__ Sbuf) {
    int gid = blockIdx.x * 256 + threadIdx.x;  // 262144
    int l = gid & 63, d = (gid >> 6) & 127, bh = gid >> 13;
    float run = 0.f;
    for (int c = 0; c < 16; ++c) {
        size_t idx = (size_t)(bh * 16 + c) * 8192 + d * 64 + l;
        float t = bf2f(Sbuf[idx]);
        Sbuf[idx] = f2bf(run);
        run += t;
    }
}

// Per (bh,c): G^T = A @ P^T (C-layout row=s,col=i), mask s<=i, pack to LDS bf16;
// Y = Gm @ V (K=128, b-frag from VT) + P @ C0 (K=64, b-frag from S bf16).
__global__ __launch_bounds__(256) void chunk_out_mfma(const ushort* __restrict__ ab,
                                                      const ushort* __restrict__ Pb,
                                                      const ushort* __restrict__ VT,
                                                      const ushort* __restrict__ S,
                                                      ushort* __restrict__ Yb) {
    __shared__ __align__(16) ushort Gs[128 * 136];  // [i][s], +8 pad kills conflicts
    int blk = blockIdx.x, bh = blk >> 4, c = blk & 15;
    int b = bh >> 3, h = bh & 7;
    int w = threadIdx.x >> 6, lane = threadIdx.x & 63;
    int quad = lane >> 4, l15 = lane & 15;
    const ushort* Pc = Pb + (size_t)(bh * 2048 + c * 128) * 64;
    const ushort* Ac = ab + (size_t)(bh * 2048 + c * 128) * 64;
    // Phase 1: G^T = A @ P^T for cols i in [w*32, w*32+32)
    f32x4 g[8][2] = {};
#pragma unroll
    for (int ks = 0; ks < 2; ++ks) {
        bf16x8 bfr[2];
#pragma unroll
        for (int ni = 0; ni < 2; ++ni)
            bfr[ni] = *(const bf16x8*)(Pc + (w * 32 + ni * 16 + l15) * 64 + ks * 32 + quad * 8);
#pragma unroll
        for (int ms = 0; ms < 8; ++ms) {
            bf16x8 af = *(const bf16x8*)(Ac + (ms * 16 + l15) * 64 + ks * 32 + quad * 8);
#pragma unroll
            for (int ni = 0; ni < 2; ++ni)
                g[ms][ni] = __builtin_amdgcn_mfma_f32_16x16x32_bf16(af, bfr[ni], g[ms][ni], 0, 0, 0);
        }
    }
#pragma unroll
    for (int ms = 0; ms < 8; ++ms)
#pragma unroll
        for (int ni = 0; ni < 2; ++ni) {
            int iL = w * 32 + ni * 16 + l15;
            int sBase = ms * 16 + quad * 4;
            f32x4 v = g[ms][ni];
            ushort4 o;
            o.x = (sBase + 0 <= iL) ? f2bf(v[0]) : (ushort)0;
            o.y = (sBase + 1 <= iL) ? f2bf(v[1]) : (ushort)0;
            o.z = (sBase + 2 <= iL) ? f2bf(v[2]) : (ushort)0;
            o.w = (sBase + 3 <= iL) ? f2bf(v[3]) : (ushort)0;
            *(ushort4*)(Gs + iL * 136 + sBase) = o;
        }
    __syncthreads();
    // Phase 2: Y rows i in [w*32, w*32+32)
    const ushort* vtb = VT + (size_t)bh * 128 * 2048 + c * 128;
    const ushort* sp = S + (size_t)blk * 8192;
    f32x4 y[2][8] = {};
#pragma unroll
    for (int ks = 0; ks < 4; ++ks) {
        bf16x8 af[2];
#pragma unroll
        for (int mi = 0; mi < 2; ++mi)
            af[mi] = *(const bf16x8*)(Gs + (w * 32 + mi * 16 + l15) * 136 + ks * 32 + quad * 8);
#pragma unroll
        for (int nj = 0; nj < 8; ++nj) {
            bf16x8 bfr = *(const bf16x8*)(vtb + (size_t)(nj * 16 + l15) * 2048 + ks * 32 + quad * 8);
#pragma unroll
            for (int mi = 0; mi < 2; ++mi)
                y[mi][nj] = __builtin_amdgcn_mfma_f32_16x16x32_bf16(af[mi], bfr, y[mi][nj], 0, 0, 0);
        }
    }
#pragma unroll
    for (int ks = 0; ks < 2; ++ks) {
        bf16x8 af[2];
#pragma unroll
        for (int mi = 0; mi < 2; ++mi)
            af[mi] = *(const bf16x8*)(Pc + (w * 32 + mi * 16 + l15) * 64 + ks * 32 + quad * 8);
#pragma unroll
        for (int nj = 0; nj < 8; ++nj) {
            bf16x8 bfr = *(const bf16x8*)(sp + (nj * 16 + l15) * 64 + ks * 32 + quad * 8);
#pragma unroll
            for (int mi = 0; mi < 2; ++mi)
                y[mi][nj] = __builtin_amdgcn_mfma_f32_16x16x32_bf16(af[mi], bfr, y[mi][nj], 0, 0, 0);
        }
    }
    ushort* yout = Yb + ((size_t)(b * 2048 + c * 128)) * 1024 + h * 128;
#pragma unroll
    for (int mi = 0; mi < 2; ++mi)
#pragma unroll
        for (int nj = 0; nj < 8; ++nj) {
            f32x4 v = y[mi][nj];
#pragma unroll
            for (int r = 0; r < 4; ++r) {
                int iL = w * 32 + mi * 16 + quad * 4 + r;
                yout[(size_t)iL * 1024 + nj * 16 + l15] = f2bf(v[r]);
            }
        }
}

// Plain GEMM, fp32 C natural (final out = Y @ Wo).
__global__ __launch_bounds__(256) void mfma_gemm(const ushort* __restrict__ A,
                                                 const ushort* __restrict__ BT,
                                                 float* __restrict__ Cf,
                                                 int M, int N, int K) {
    __shared__ __align__(16) ushort As[128 * 32];
    __shared__ __align__(16) ushort Bs[128 * 32];
    const int tid = threadIdx.x;
    const int w = tid >> 6, lane = tid & 63;
    const int quad = lane >> 4, l15 = lane & 15;
    const int m0 = blockIdx.y * 128, n0 = blockIdx.x * 128;
    const int wm = (w & 1) * 64, wn = (w >> 1) * 64;
    f32x4 acc[4][4] = {};
    const int r0 = tid >> 2, kc = (tid & 3) * 8;
    const int r1 = 64 + r0;
    const ushort* Arow0 = A + (size_t)(m0 + r0) * K + kc;
    const ushort* Arow1 = A + (size_t)(m0 + r1) * K + kc;
    const ushort* Brow0 = BT + (size_t)(n0 + r0) * K + kc;
    const ushort* Brow1 = BT + (size_t)(n0 + r1) * K + kc;
    ushort* AsW0 = As + (w * 64) * 8;
    ushort* AsW1 = As + (256 + w * 64) * 8;
    ushort* BsW0 = Bs + (w * 64) * 8;
    ushort* BsW1 = Bs + (256 + w * 64) * 8;
    const ushort* afp = As + (wm + l15) * 32 + quad * 8;
    const ushort* bfp = Bs + (wn + l15) * 32 + quad * 8;
    for (int k0 = 0; k0 < K; k0 += 32) {
        gload_lds16(Arow0 + k0, AsW0);
        gload_lds16(Arow1 + k0, AsW1);
        gload_lds16(Brow0 + k0, BsW0);
        gload_lds16(Brow1 + k0, BsW1);
        __syncthreads();
        bf16x8 af[4], bf[4];
#pragma unroll
        for (int i = 0; i < 4; ++i) {
            af[i] = *(const bf16x8*)(afp + i * 16 * 32);
            bf[i] = *(const bf16x8*)(bfp + i * 16 * 32);
        }
#pragma unroll
        for (int i = 0; i < 4; ++i)
#pragma unroll
            for (int j = 0; j < 4; ++j)
                acc[i][j] = __builtin_amdgcn_mfma_f32_16x16x32_bf16(af[i], bf[j], acc[i][j], 0, 0, 0);
        __syncthreads();
    }
    const int crow = m0 + wm + quad * 4;
    const int ccol = n0 + wn + l15;
#pragma unroll
    for (int i = 0; i < 4; ++i)
#pragma unroll
        for (int j = 0; j < 4; ++j) {
            f32x4 v = acc[i][j];
#pragma unroll
            for (int r = 0; r < 4; ++r)
                Cf[(size_t)(crow + i * 16 + r) * N + ccol + j * 16] = v[r];
        }
}

extern "C" void kernel_launch(void* const* d_in, const int* in_sizes, int n_in,
                              void* d_out, int out_size, void* d_ws, size_t ws_size,
                              hipStream_t stream) {
    const float* X  = (const float*)d_in[0];
    const float* Wk = (const float*)d_in[1];
    const float* Wq = (const float*)d_in[2];
    const float* Wv = (const float*)d_in[3];
    const float* Wo = (const float*)d_in[4];
    float* ws = (float*)d_ws;
    // float-unit offsets; total ~82 MB
    ushort* Xb   = (ushort*)ws;                  // bf16 X [8192,1024]; reused as Yb
    ushort* Qs   = (ushort*)(ws + 4194304);      // bf16 Qs [8192,512]
    ushort* Kb   = (ushort*)(ws + 6291456);      // bf16 K  [8192,512]
    ushort* VT   = (ushort*)(ws + 8388608);      // bf16 VT [32][128][2048]
    ushort* ab   = (ushort*)(ws + 12582912);     // bf16 a  [32][2048][64]
    ushort* Pb   = (ushort*)(ws + 14680064);     // bf16 P  [32][2048][64]
    ushort* Sb   = (ushort*)(ws + 16777216);     // bf16 S  [512][128][64]
    ushort* WqkT = (ushort*)(ws + 18874368);     // bf16 [1024][1024]
    ushort* WvT  = (ushort*)(ws + 19398656);     // bf16 [1024][1024]
    ushort* WoT  = (ushort*)(ws + 19922944);     // bf16 [1024][1024]
    ushort* Yb = Xb;
    float* out = (float*)d_out;
    float* mbuf = out;            // stats in d_out (overwritten by final GEMM)
    float* sbuf = out + 32768;

    dim3 blk(256);
    prep_inputs_kernel<<<11264, blk, 0, stream>>>(X, Wq, Wk, Wv, Wo, Xb, WqkT, WvT, WoT);
    qkv_gemm<<<dim3(16, 64), blk, 0, stream>>>(Xb, WqkT, WvT, Qs, Kb, VT, mbuf, sbuf);
    prep_scan_sums_kernel<<<512, blk, 0, stream>>>(Kb, Qs, mbuf, sbuf, VT, ab, Pb, Sb);
    chunk_prefix_kernel<<<1024, blk, 0, stream>>>(Sb);
    chunk_out_mfma<<<512, blk, 0, stream>>>(ab, Pb, VT, Sb, Yb);
    mfma_gemm<<<dim3(8, 64), blk, 0, stream>>>(Yb, WoT, out, 8192, 1024, 1024);
}